// Round 5
// baseline (147.905 us; speedup 1.0000x reference)
//
#include <hip/hip_runtime.h>
#include <hip/hip_bf16.h>

#define B_ 128
#define H_ 1024
#define L_ 60
#define V_ 50257

typedef __attribute__((ext_vector_type(8))) short bf16x8;
typedef __attribute__((ext_vector_type(4))) float f32x4;

__device__ __forceinline__ unsigned short f2bf(float f) {
  union { __hip_bfloat16 h; unsigned short u; } v;
  v.h = __float2bfloat16(f);
  return v.u;
}

__device__ __forceinline__ bf16x8 cvt8(float4 a, float4 b) {
  union { bf16x8 v; __hip_bfloat16 h[8]; } u;
  u.h[0] = __float2bfloat16(a.x); u.h[1] = __float2bfloat16(a.y);
  u.h[2] = __float2bfloat16(a.z); u.h[3] = __float2bfloat16(a.w);
  u.h[4] = __float2bfloat16(b.x); u.h[5] = __float2bfloat16(b.y);
  u.h[6] = __float2bfloat16(b.z); u.h[7] = __float2bfloat16(b.w);
  return u.v;
}

__device__ __forceinline__ void gl_lds16(const void* g, void* l) {
  __builtin_amdgcn_global_load_lds(
      (const __attribute__((address_space(1))) unsigned int*)g,
      (__attribute__((address_space(3))) unsigned int*)l, 16, 0, 0);
}

#define SBAR()   __builtin_amdgcn_s_barrier()
#define SCHED0() __builtin_amdgcn_sched_barrier(0)
__device__ __forceinline__ void vwait4() { asm volatile("s_waitcnt vmcnt(4)" ::: "memory"); }
__device__ __forceinline__ void vwait0() { asm volatile("s_waitcnt vmcnt(0)" ::: "memory"); }

// bf16 A-fragment pack position for MFMA 16x16x32 (verified R1-R4):
// fragment ((s*8+bm)*64+lane), elem j ; lane holds A[row=l&15][k=(l>>4)*8+j]
__device__ __forceinline__ size_t packIdx(int b, int k) {
  int s = k >> 5;
  int bm = b >> 4;
  int lane = (b & 15) | (((k >> 3) & 3) << 4);
  return ((size_t)((s * 8 + bm) * 64 + lane) << 3) | (size_t)(k & 7);
}

// ------------- pack embedded + hidden into fragment layout -------------
__global__ __launch_bounds__(256) void k_embh(
    const int* __restrict__ input, const float* __restrict__ hidden,
    const float* __restrict__ emb, unsigned short* __restrict__ aXa,
    unsigned short* __restrict__ aH)
{
  int idx = blockIdx.x * 256 + threadIdx.x;  // B_*H_
  int b = idx >> 10, j = idx & (H_ - 1);
  float e = emb[(size_t)input[b] * H_ + j];
  float h = hidden[idx];
  size_t p = packIdx(b, j);
  aXa[p] = f2bf(e);
  aH[p]  = f2bf(h);
}

// ------------- attention logits: one wave per (b,l) -------------
__global__ __launch_bounds__(256) void k_alog(
    const int* __restrict__ input, const float* __restrict__ hidden,
    const float* __restrict__ emb, const float* __restrict__ attn_W,
    const float* __restrict__ attn_b, float* __restrict__ lbuf)
{
  int t = threadIdx.x, wv = t >> 6, lane = t & 63;
  int task = blockIdx.x * 4 + wv;            // 0 .. B_*L_-1
  int b = task / L_, l = task - b * L_;
  const float* erow = emb + (size_t)input[b] * H_;
  const float* hrow = hidden + (size_t)b * H_;
  const float* wr = attn_W + (size_t)l * (2 * H_);
  float acc = 0.f;
  #pragma unroll 4
  for (int i = 0; i < 16; ++i) {
    int m = lane + i * 64;
    acc += erow[m] * wr[m] + hrow[m] * wr[H_ + m];
  }
  #pragma unroll
  for (int off = 32; off; off >>= 1) acc += __shfl_xor(acc, off);
  if (lane == 0) lbuf[b * 64 + l] = acc + attn_b[l];
}

// ------------- attention softmax: one wave per b -------------
__global__ __launch_bounds__(256) void k_asm(
    const float* __restrict__ lbuf, float* __restrict__ attnw,
    float* __restrict__ wbuf)
{
  int t = threadIdx.x, wv = t >> 6, lane = t & 63;
  int b = blockIdx.x * 4 + wv;
  float v = (lane < L_) ? lbuf[b * 64 + lane] : -1e30f;
  float m = v;
  #pragma unroll
  for (int off = 32; off; off >>= 1) m = fmaxf(m, __shfl_xor(m, off));
  float e = (lane < L_) ? __expf(v - m) : 0.f;
  float s = e;
  #pragma unroll
  for (int off = 32; off; off >>= 1) s += __shfl_xor(s, off);
  float w = e / s;
  if (lane < L_) { attnw[b * L_ + lane] = w; wbuf[b * 64 + lane] = w; }
}

// ------------- attention weighted sum over enc, pack into aXa[k>=H] -------------
__global__ __launch_bounds__(256) void k_app(
    const float* __restrict__ enc, const float* __restrict__ wbuf,
    unsigned short* __restrict__ aXa)
{
  __shared__ float sWt[64];
  int b = blockIdx.x, q = blockIdx.y, t = threadIdx.x;
  if (t < L_) sWt[t] = wbuf[b * 64 + t];
  __syncthreads();
  int col = q * 256 + t;
  const float* eb = enc + (size_t)b * L_ * H_ + col;
  float acc = 0.f;
  #pragma unroll 4
  for (int l = 0; l < L_; ++l) acc += sWt[l] * eb[(size_t)l * H_];
  aXa[packIdx(b, H_ + col)] = f2bf(acc);
}

// ------------- LDS-staged MFMA GEMM, ring-3 counted-vmcnt pipeline -------------
// C[b,n] = sum_k A[b,k]*W[n,k]. Tile 128(B) x 64(N), BK=32. Per chunk: W 8KB
// (XOR-swizzled both sides) + A 8KB (linear), staged via global_load_lds.
// Ring of 3 buffers, ONE barrier per chunk:
//   vwait(4) [own chunk-kk loads landed] -> s_barrier [all waves: kk landed,
//   all done reading kk-1] -> STAGE(kk+2 -> buf[(kk+2)%3], overwrites kk-1's
//   buffer: safe] -> compute(kk). Tail: vwait0. vmcnt never drained mid-loop.
// Wave w: rows [32w,32w+32) x 4 nc col-tiles. Split-K via blockIdx.y.
// halfY>0: fused pair (y>=halfY uses Apk2/Wt2/Cpart2).
// pms!=null: emit per-(row, blockx) softmax partials (max, expsum).
__global__ __launch_bounds__(256) void k_gemm(
    const unsigned short* __restrict__ Apk, const unsigned short* __restrict__ Apk2,
    const float* __restrict__ Wt, const float* __restrict__ Wt2,
    const float* __restrict__ bias, float* __restrict__ Cdir,
    float* __restrict__ Cpart, float* __restrict__ Cpart2,
    float* __restrict__ pms, int K, int N, int nchunks, int halfY, int nblkx)
{
  __shared__ __align__(16) float bufW[3][64 * 32];            // 3 x 8KB
  __shared__ __align__(16) unsigned short bufA[3][128 * 32];  // 3 x 8KB
  int t = threadIdx.x, wv = t >> 6, lane = t & 63;
  int y = blockIdx.y;
  const unsigned short* A = Apk;
  const float* W = Wt;
  float* CP = Cpart;
  int sidx = y;
  if (halfY && y >= halfY) { A = Apk2; W = Wt2; CP = Cpart2; sidx = y - halfY; }
  int chunk0 = sidx * nchunks;
  int n0 = blockIdx.x * 64;
  int bm0 = wv * 2;
  int srow8 = lane >> 3;     // row within 8-row staging group
  int sch = lane & 7;        // 16B chunk within 128B row

  f32x4 acc[2][4];
  #pragma unroll
  for (int i = 0; i < 2; ++i)
    #pragma unroll
    for (int j = 0; j < 4; ++j) acc[i][j] = (f32x4){0.f, 0.f, 0.f, 0.f};

  auto STAGE = [&](int kc, int bi) {
    #pragma unroll
    for (int i = 0; i < 2; ++i) {
      int r = wv * 16 + i * 8 + srow8;
      int gcol = n0 + r; gcol = (gcol < N) ? gcol : (N - 1);
      int c = sch ^ (r & 7);
      const float* src = W + (size_t)gcol * K + (size_t)kc * 32 + c * 4;
      gl_lds16(src, &bufW[bi][(wv * 16 + i * 8) * 32]);
    }
    #pragma unroll
    for (int j = 0; j < 2; ++j) {
      const unsigned short* src = A + ((size_t)kc * 8 + bm0 + j) * 512 + lane * 8;
      gl_lds16(src, &bufA[bi][(bm0 + j) * 512]);
    }
  };

  STAGE(chunk0, 0);
  STAGE(chunk0 + 1, 1);

  int g = lane >> 4;
  int bi = 0;
  for (int kk = 0; kk < nchunks; ++kk) {
    if (kk < nchunks - 1) vwait4(); else vwait0();
    SCHED0(); SBAR(); SCHED0();
    if (kk + 2 < nchunks) {
      int bi2 = bi + 2; if (bi2 >= 3) bi2 -= 3;
      STAGE(chunk0 + kk + 2, bi2);
    }
    const float* bw = bufW[bi];
    const unsigned short* ba = bufA[bi];
    bf16x8 a0 = *(const bf16x8*)&ba[(bm0) * 512 + lane * 8];
    bf16x8 a1 = *(const bf16x8*)&ba[(bm0 + 1) * 512 + lane * 8];
    #pragma unroll
    for (int nc = 0; nc < 4; ++nc) {
      int rr = nc * 16 + (lane & 15);
      int c0 = (g * 2) ^ (rr & 7);
      int c1 = (g * 2 + 1) ^ (rr & 7);
      float4 w0 = *(const float4*)&bw[rr * 32 + c0 * 4];
      float4 w1 = *(const float4*)&bw[rr * 32 + c1 * 4];
      bf16x8 bfr = cvt8(w0, w1);
      acc[0][nc] = __builtin_amdgcn_mfma_f32_16x16x32_bf16(a0, bfr, acc[0][nc], 0, 0, 0);
      acc[1][nc] = __builtin_amdgcn_mfma_f32_16x16x32_bf16(a1, bfr, acc[1][nc], 0, 0, 0);
    }
    bi = (bi == 2) ? 0 : bi + 1;
  }

  int cols[4]; float bv[4];
  #pragma unroll
  for (int nc = 0; nc < 4; ++nc) {
    int c = n0 + nc * 16 + (lane & 15);
    cols[nc] = c;
    bv[nc] = (bias && c < N) ? bias[c] : 0.f;
  }
  int rb = (lane >> 4) * 4;
  if (CP) {
    float* dst = CP + (size_t)sidx * B_ * N;
    #pragma unroll
    for (int bm = 0; bm < 2; ++bm)
      #pragma unroll
      for (int r = 0; r < 4; ++r) {
        int row = (bm0 + bm) * 16 + rb + r;
        #pragma unroll
        for (int nc = 0; nc < 4; ++nc)
          if (cols[nc] < N) dst[(size_t)row * N + cols[nc]] = acc[bm][nc][r];
      }
  } else {
    #pragma unroll
    for (int bm = 0; bm < 2; ++bm)
      #pragma unroll
      for (int r = 0; r < 4; ++r) {
        int row = (bm0 + bm) * 16 + rb + r;
        #pragma unroll
        for (int nc = 0; nc < 4; ++nc)
          if (cols[nc] < N) Cdir[(size_t)row * N + cols[nc]] = acc[bm][nc][r] + bv[nc];
      }
    if (pms) {
      #pragma unroll
      for (int bm = 0; bm < 2; ++bm)
        #pragma unroll
        for (int r = 0; r < 4; ++r) {
          int row = (bm0 + bm) * 16 + rb + r;
          float m = -1e30f;
          #pragma unroll
          for (int nc = 0; nc < 4; ++nc)
            if (cols[nc] < N) m = fmaxf(m, acc[bm][nc][r] + bv[nc]);
          #pragma unroll
          for (int off = 8; off; off >>= 1) m = fmaxf(m, __shfl_xor(m, off));
          float e = 0.f;
          #pragma unroll
          for (int nc = 0; nc < 4; ++nc)
            if (cols[nc] < N) e += __expf(acc[bm][nc][r] + bv[nc] - m);
          #pragma unroll
          for (int off = 8; off; off >>= 1) e += __shfl_xor(e, off);
          if ((lane & 15) == 0) {
            size_t o = ((size_t)row * nblkx + blockIdx.x) * 2;
            pms[o] = m; pms[o + 1] = e;
          }
        }
    }
  }
}

// ------------- reduce combine partials (16) + bias + relu -> packed x -------------
__global__ __launch_bounds__(256) void k_reduce_comb(
    const float* __restrict__ parts, const float* __restrict__ bias,
    unsigned short* __restrict__ aX)
{
  int idx = blockIdx.x * 256 + threadIdx.x;  // B_*H_
  int b = idx >> 10, j = idx & (H_ - 1);
  float s = bias[j];
  #pragma unroll
  for (int p = 0; p < 16; ++p) s += parts[(size_t)p * B_ * H_ + idx];
  s = fmaxf(s, 0.f);
  aX[packIdx(b, j)] = f2bf(s);
}

// ------------- GRU gates from split partials (4+4) -> h_new (+packed) -------------
__global__ __launch_bounds__(256) void k_gate(
    const float* __restrict__ giP, const float* __restrict__ ghP,
    const float* __restrict__ b_ih, const float* __restrict__ b_hh,
    const float* __restrict__ hidden, float* __restrict__ hnew,
    unsigned short* __restrict__ aHn)
{
  int idx = blockIdx.x * 256 + threadIdx.x;  // B_*H_
  int b = idx >> 10, j = idx & (H_ - 1);
  size_t base = (size_t)b * 3 * H_;
  float ir = b_ih[j], iz = b_ih[H_ + j], in_ = b_ih[2 * H_ + j];
  float hr = b_hh[j], hz = b_hh[H_ + j], hn = b_hh[2 * H_ + j];
  #pragma unroll
  for (int p = 0; p < 4; ++p) {
    const float* gi = giP + (size_t)p * B_ * 3 * H_ + base;
    const float* gh = ghP + (size_t)p * B_ * 3 * H_ + base;
    ir += gi[j]; iz += gi[H_ + j]; in_ += gi[2 * H_ + j];
    hr += gh[j]; hz += gh[H_ + j]; hn += gh[2 * H_ + j];
  }
  float r = 1.f / (1.f + __expf(-(ir + hr)));
  float z = 1.f / (1.f + __expf(-(iz + hz)));
  float n = tanhf(in_ + r * hn);
  float h = hidden[idx];
  float hv = (1.f - z) * n + z * h;
  hnew[idx] = hv;
  aHn[packIdx(b, j)] = f2bf(hv);
}

// ------------- log_softmax: per-block redundant reduce of pms + subtract -------------
#define SL_ 6283
__global__ __launch_bounds__(256) void k_lsub(
    float* __restrict__ logits, const float* __restrict__ pms, int nblk)
{
  __shared__ float sm[4], ss[4], sc;
  int b = blockIdx.x, sl = blockIdx.y, t = threadIdx.x;
  float M = -1e30f, S = 0.f;
  for (int i = t; i < nblk; i += 256) {
    float m = pms[((size_t)b * nblk + i) * 2];
    float s = pms[((size_t)b * nblk + i) * 2 + 1];
    float nm = fmaxf(M, m);
    S = S * __expf(M - nm) + s * __expf(m - nm);
    M = nm;
  }
  #pragma unroll
  for (int off = 32; off; off >>= 1) {
    float m2 = __shfl_xor(M, off), s2 = __shfl_xor(S, off);
    float nm = fmaxf(M, m2);
    S = S * __expf(M - nm) + s2 * __expf(m2 - nm);
    M = nm;
  }
  if ((t & 63) == 0) { sm[t >> 6] = M; ss[t >> 6] = S; }
  __syncthreads();
  if (t == 0) {
    float Mf = sm[0], Sf = ss[0];
    #pragma unroll
    for (int i = 1; i < 4; ++i) {
      float nm = fmaxf(Mf, sm[i]);
      Sf = Sf * __expf(Mf - nm) + ss[i] * __expf(sm[i] - nm);
      Mf = nm;
    }
    sc = Mf + logf(Sf);
  }
  __syncthreads();
  float c = sc;
  int v0 = sl * SL_;
  int v1 = v0 + SL_; if (v1 > V_) v1 = V_;
  float* row = logits + (size_t)b * V_;
  for (int v = v0 + t; v < v1; v += 256) row[v] -= c;
}

extern "C" void kernel_launch(void* const* d_in, const int* in_sizes, int n_in,
                              void* d_out, int out_size, void* d_ws, size_t ws_size,
                              hipStream_t stream)
{
  const int*   input  = (const int*)d_in[0];
  const float* hidden = (const float*)d_in[1];
  const float* enc    = (const float*)d_in[2];
  const float* emb    = (const float*)d_in[3];
  const float* attn_W = (const float*)d_in[4];
  const float* attn_b = (const float*)d_in[5];
  const float* comb_W = (const float*)d_in[6];
  const float* comb_b = (const float*)d_in[7];
  const float* W_ih   = (const float*)d_in[8];
  const float* W_hh   = (const float*)d_in[9];
  const float* b_ih   = (const float*)d_in[10];
  const float* b_hh   = (const float*)d_in[11];
  const float* out_W  = (const float*)d_in[12];
  const float* out_b  = (const float*)d_in[13];

  float* out    = (float*)d_out;
  float* logits = out;                        // [B,V]
  float* hnew   = out + (size_t)B_ * V_;      // [1,B,H]
  float* attnw  = hnew + (size_t)B_ * H_;     // [B,L]

  const int NBLK = (V_ + 63) / 64;            // 786
  char* ws = (char*)d_ws;
  unsigned short* aXa = (unsigned short*)(ws);                 // 512K
  unsigned short* aH  = (unsigned short*)(ws + 524288);        // 256K
  unsigned short* aX  = (unsigned short*)(ws + 786432);        // 256K
  unsigned short* aHn = (unsigned short*)(ws + 1048576);       // 256K
  float* wbuf  = (float*)(ws + 1310720);                       // 32K
  float* lbuf  = (float*)(ws + 1343488);                       // 32K
  float* pms   = (float*)(ws + 1376256);                       // 805K
  // scratch region (aliased): combP (16 x 512K = 8MB) consumed by k_reduce_comb
  // BEFORE giP/ghP (4 x 1.5MB each) are produced by the gi|gh GEMM.
  float* combP = (float*)(ws + 2185216);                       // 8MB
  float* giP   = (float*)(ws + 2185216);                       // 6MB (aliases combP)
  float* ghP   = (float*)(ws + 2185216 + 6291456);             // 6MB

  // 1. pack embedded + hidden
  k_embh<<<512, 256, 0, stream>>>(input, hidden, emb, aXa, aH);
  // 2. attention logits (wave per (b,l))
  k_alog<<<(B_ * L_) / 4, 256, 0, stream>>>(input, hidden, emb, attn_W, attn_b, lbuf);
  // 3. attention softmax
  k_asm<<<B_ / 4, 256, 0, stream>>>(lbuf, attnw, wbuf);
  // 4. attention weighted sum; pack into aXa hi
  k_app<<<dim3(B_, 4), 256, 0, stream>>>(enc, wbuf, aXa);
  // 5. combine GEMM: K=2048 (64 chunks), 16 splits x 4 chunks
  k_gemm<<<dim3(16, 16), 256, 0, stream>>>(aXa, nullptr, comb_W, nullptr, nullptr,
                                           nullptr, combP, nullptr, nullptr,
                                           2 * H_, H_, 4, 0, 0);
  // 6. reduce + bias + relu -> packed x
  k_reduce_comb<<<(B_ * H_) / 256, 256, 0, stream>>>(combP, comb_b, aX);
  // 7. fused gi|gh GEMMs: K=1024 (32 chunks), each 4 splits x 8 chunks
  k_gemm<<<dim3(48, 8), 256, 0, stream>>>(aX, aH, W_ih, W_hh, nullptr,
                                          nullptr, giP, ghP, nullptr,
                                          H_, 3 * H_, 8, 4, 0);
  // 8. gates -> h_new (out) + packed h_new
  k_gate<<<(B_ * H_) / 256, 256, 0, stream>>>(giP, ghP, b_ih, b_hh, hidden, hnew, aHn);
  // 9. projection + bias + softmax partials (K=1024 -> 32 chunks, no split)
  k_gemm<<<dim3(NBLK, 1), 256, 0, stream>>>(aHn, nullptr, out_W, nullptr, out_b,
                                            logits, nullptr, nullptr, pms,
                                            H_, V_, 32, 0, NBLK);
  // 10. fused reduce + subtract
  k_lsub<<<dim3(B_, 8), 256, 0, stream>>>(logits, pms, NBLK);
}

// Round 6
// 135.125 us; speedup vs baseline: 1.0946x; 1.0946x over previous
//
#include <hip/hip_runtime.h>
#include <hip/hip_bf16.h>

#define B_ 128
#define H_ 1024
#define L_ 60
#define V_ 50257

typedef __attribute__((ext_vector_type(8))) short bf16x8;
typedef __attribute__((ext_vector_type(4))) float f32x4;

__device__ __forceinline__ unsigned short f2bf(float f) {
  union { __hip_bfloat16 h; unsigned short u; } v;
  v.h = __float2bfloat16(f);
  return v.u;
}

__device__ __forceinline__ bf16x8 cvt8(float4 a, float4 b) {
  union { bf16x8 v; __hip_bfloat16 h[8]; } u;
  u.h[0] = __float2bfloat16(a.x); u.h[1] = __float2bfloat16(a.y);
  u.h[2] = __float2bfloat16(a.z); u.h[3] = __float2bfloat16(a.w);
  u.h[4] = __float2bfloat16(b.x); u.h[5] = __float2bfloat16(b.y);
  u.h[6] = __float2bfloat16(b.z); u.h[7] = __float2bfloat16(b.w);
  return u.v;
}

__device__ __forceinline__ void gl_lds16(const void* g, void* l) {
  __builtin_amdgcn_global_load_lds(
      (const __attribute__((address_space(1))) unsigned int*)g,
      (__attribute__((address_space(3))) unsigned int*)l, 16, 0, 0);
}

#define SBAR()   __builtin_amdgcn_s_barrier()
#define SCHED0() __builtin_amdgcn_sched_barrier(0)
__device__ __forceinline__ void vwait4() { asm volatile("s_waitcnt vmcnt(4)" ::: "memory"); }
__device__ __forceinline__ void vwait0() { asm volatile("s_waitcnt vmcnt(0)" ::: "memory"); }

// bf16 A-fragment pack position for MFMA 16x16x32 (verified R1-R5):
// fragment ((s*8+bm)*64+lane), elem j ; lane holds A[row=l&15][k=(l>>4)*8+j]
__device__ __forceinline__ size_t packIdx(int b, int k) {
  int s = k >> 5;
  int bm = b >> 4;
  int lane = (b & 15) | (((k >> 3) & 3) << 4);
  return ((size_t)((s * 8 + bm) * 64 + lane) << 3) | (size_t)(k & 7);
}

// ------------- pack embedded + hidden into fragment layout -------------
__global__ __launch_bounds__(256) void k_embh(
    const int* __restrict__ input, const float* __restrict__ hidden,
    const float* __restrict__ emb, unsigned short* __restrict__ aXa,
    unsigned short* __restrict__ aH)
{
  int idx = blockIdx.x * 256 + threadIdx.x;  // B_*H_
  int b = idx >> 10, j = idx & (H_ - 1);
  float e = emb[(size_t)input[b] * H_ + j];
  float h = hidden[idx];
  size_t p = packIdx(b, j);
  aXa[p] = f2bf(e);
  aH[p]  = f2bf(h);
}

// ------------- attention logits: one wave per (b,l) -------------
__global__ __launch_bounds__(256) void k_alog(
    const int* __restrict__ input, const float* __restrict__ hidden,
    const float* __restrict__ emb, const float* __restrict__ attn_W,
    const float* __restrict__ attn_b, float* __restrict__ lbuf)
{
  int t = threadIdx.x, wv = t >> 6, lane = t & 63;
  int task = blockIdx.x * 4 + wv;            // 0 .. B_*L_-1
  int b = task / L_, l = task - b * L_;
  const float* erow = emb + (size_t)input[b] * H_;
  const float* hrow = hidden + (size_t)b * H_;
  const float* wr = attn_W + (size_t)l * (2 * H_);
  float acc = 0.f;
  #pragma unroll 4
  for (int i = 0; i < 16; ++i) {
    int m = lane + i * 64;
    acc += erow[m] * wr[m] + hrow[m] * wr[H_ + m];
  }
  #pragma unroll
  for (int off = 32; off; off >>= 1) acc += __shfl_xor(acc, off);
  if (lane == 0) lbuf[b * 64 + l] = acc + attn_b[l];
}

// ------------- attention softmax: one wave per b -------------
__global__ __launch_bounds__(256) void k_asm(
    const float* __restrict__ lbuf, float* __restrict__ attnw,
    float* __restrict__ wbuf)
{
  int t = threadIdx.x, wv = t >> 6, lane = t & 63;
  int b = blockIdx.x * 4 + wv;
  float v = (lane < L_) ? lbuf[b * 64 + lane] : -1e30f;
  float m = v;
  #pragma unroll
  for (int off = 32; off; off >>= 1) m = fmaxf(m, __shfl_xor(m, off));
  float e = (lane < L_) ? __expf(v - m) : 0.f;
  float s = e;
  #pragma unroll
  for (int off = 32; off; off >>= 1) s += __shfl_xor(s, off);
  float w = e / s;
  if (lane < L_) { attnw[b * L_ + lane] = w; wbuf[b * 64 + lane] = w; }
}

// ------------- attention weighted sum over enc, pack into aXa[k>=H] -------------
__global__ __launch_bounds__(256) void k_app(
    const float* __restrict__ enc, const float* __restrict__ wbuf,
    unsigned short* __restrict__ aXa)
{
  __shared__ float sWt[64];
  int b = blockIdx.x, q = blockIdx.y, t = threadIdx.x;
  if (t < L_) sWt[t] = wbuf[b * 64 + t];
  __syncthreads();
  int col = q * 256 + t;
  const float* eb = enc + (size_t)b * L_ * H_ + col;
  float acc = 0.f;
  #pragma unroll 4
  for (int l = 0; l < L_; ++l) acc += sWt[l] * eb[(size_t)l * H_];
  aXa[packIdx(b, H_ + col)] = f2bf(acc);
}

// ------------- LDS-staged MFMA GEMM, counted-vmcnt, W-only LDS -------------
// C[b,n] = sum_k A[b,k]*W[n,k]. Tile 128(B) x 64(N), chunk = 32 k (one MFMA step).
// W: 8KB/chunk staged to LDS via global_load_lds (XOR-swizzled both sides),
// double-buffered. A: per-wave fragments loaded straight global->VGPR,
// double-buffered in registers (static roles via x2 unroll). Per chunk a wave
// issues 4 VMEM (2 gl_lds W + 2 reg A) -> vwait4 == "previous chunk landed".
// Proven R3 2-barrier fence skeleton; vmcnt never drained mid-loop.
// LDS 16KB, __launch_bounds__(256,6) -> 6 blocks/CU.
__global__ __launch_bounds__(256, 6) void k_gemm(
    const unsigned short* __restrict__ Apk, const unsigned short* __restrict__ Apk2,
    const float* __restrict__ Wt, const float* __restrict__ Wt2,
    const float* __restrict__ bias, float* __restrict__ Cdir,
    float* __restrict__ Cpart, float* __restrict__ Cpart2,
    float* __restrict__ pms, int K, int N, int nchunks, int halfY, int nblkx)
{
  __shared__ __align__(16) float bufW0[64 * 32];   // 8KB
  __shared__ __align__(16) float bufW1[64 * 32];   // 8KB
  int t = threadIdx.x, wv = t >> 6, lane = t & 63;
  int y = blockIdx.y;
  const unsigned short* A = Apk;
  const float* W = Wt;
  float* CP = Cpart;
  int sidx = y;
  if (halfY && y >= halfY) { A = Apk2; W = Wt2; CP = Cpart2; sidx = y - halfY; }
  int chunk0 = sidx * nchunks;
  int n0 = blockIdx.x * 64;
  int bm0 = wv * 2;
  int srow8 = lane >> 3;     // row within 8-row staging group
  int sch = lane & 7;        // 16B chunk within 128B row
  int g = lane >> 4;

  f32x4 acc[2][4];
  #pragma unroll
  for (int i = 0; i < 2; ++i)
    #pragma unroll
    for (int j = 0; j < 4; ++j) acc[i][j] = (f32x4){0.f, 0.f, 0.f, 0.f};

  auto SW = [&](int kc, float* buf) {
    #pragma unroll
    for (int i = 0; i < 2; ++i) {
      int r = wv * 16 + i * 8 + srow8;
      int gcol = n0 + r; gcol = (gcol < N) ? gcol : (N - 1);
      int c = sch ^ (r & 7);
      const float* src = W + (size_t)gcol * K + (size_t)kc * 32 + c * 4;
      gl_lds16(src, buf + (wv * 16 + i * 8) * 32);
    }
  };
  const bf16x8* apg = (const bf16x8*)A;
  auto LA = [&](int kc, bf16x8& x0, bf16x8& x1) {
    x0 = apg[((size_t)kc * 8 + bm0) * 64 + lane];
    x1 = apg[((size_t)kc * 8 + bm0 + 1) * 64 + lane];
  };
  auto COMP = [&](const float* bw, bf16x8 a0, bf16x8 a1) {
    #pragma unroll
    for (int nc = 0; nc < 4; ++nc) {
      int rr = nc * 16 + (lane & 15);
      int c0 = (g * 2) ^ (rr & 7);
      int c1 = (g * 2 + 1) ^ (rr & 7);
      float4 w0 = *(const float4*)&bw[rr * 32 + c0 * 4];
      float4 w1 = *(const float4*)&bw[rr * 32 + c1 * 4];
      bf16x8 bfr = cvt8(w0, w1);
      acc[0][nc] = __builtin_amdgcn_mfma_f32_16x16x32_bf16(a0, bfr, acc[0][nc], 0, 0, 0);
      acc[1][nc] = __builtin_amdgcn_mfma_f32_16x16x32_bf16(a1, bfr, acc[1][nc], 0, 0, 0);
    }
  };

  bf16x8 aA0, aA1, aB0, aB1;
  SW(chunk0, bufW0);     LA(chunk0, aA0, aA1);
  SW(chunk0 + 1, bufW1); LA(chunk0 + 1, aB0, aB1);
  vwait4(); SCHED0(); SBAR();

  for (int kk = 0; kk < nchunks; kk += 2) {
    COMP(bufW0, aA0, aA1);                      // chunk kk
    SCHED0(); SBAR();                           // all waves done with bufW0
    if (kk + 2 < nchunks) { SW(chunk0 + kk + 2, bufW0); LA(chunk0 + kk + 2, aA0, aA1); vwait4(); }
    else vwait0();
    SCHED0(); SBAR();                           // bufW1 / aB landed everywhere
    COMP(bufW1, aB0, aB1);                      // chunk kk+1
    if (kk + 2 < nchunks) {
      SCHED0(); SBAR();                         // all waves done with bufW1
      if (kk + 3 < nchunks) { SW(chunk0 + kk + 3, bufW1); LA(chunk0 + kk + 3, aB0, aB1); vwait4(); }
      else vwait0();
      SCHED0(); SBAR();                         // bufW0 / aA landed everywhere
    }
  }

  int cols[4]; float bv[4];
  #pragma unroll
  for (int nc = 0; nc < 4; ++nc) {
    int c = n0 + nc * 16 + (lane & 15);
    cols[nc] = c;
    bv[nc] = (bias && c < N) ? bias[c] : 0.f;
  }
  int rb = (lane >> 4) * 4;
  if (CP) {
    float* dst = CP + (size_t)sidx * B_ * N;
    #pragma unroll
    for (int bm = 0; bm < 2; ++bm)
      #pragma unroll
      for (int r = 0; r < 4; ++r) {
        int row = (bm0 + bm) * 16 + rb + r;
        #pragma unroll
        for (int nc = 0; nc < 4; ++nc)
          if (cols[nc] < N) dst[(size_t)row * N + cols[nc]] = acc[bm][nc][r];
      }
  } else {
    #pragma unroll
    for (int bm = 0; bm < 2; ++bm)
      #pragma unroll
      for (int r = 0; r < 4; ++r) {
        int row = (bm0 + bm) * 16 + rb + r;
        #pragma unroll
        for (int nc = 0; nc < 4; ++nc)
          if (cols[nc] < N) Cdir[(size_t)row * N + cols[nc]] = acc[bm][nc][r] + bv[nc];
      }
    if (pms) {
      #pragma unroll
      for (int bm = 0; bm < 2; ++bm)
        #pragma unroll
        for (int r = 0; r < 4; ++r) {
          int row = (bm0 + bm) * 16 + rb + r;
          float m = -1e30f;
          #pragma unroll
          for (int nc = 0; nc < 4; ++nc)
            if (cols[nc] < N) m = fmaxf(m, acc[bm][nc][r] + bv[nc]);
          #pragma unroll
          for (int off = 8; off; off >>= 1) m = fmaxf(m, __shfl_xor(m, off));
          float e = 0.f;
          #pragma unroll
          for (int nc = 0; nc < 4; ++nc)
            if (cols[nc] < N) e += __expf(acc[bm][nc][r] + bv[nc] - m);
          #pragma unroll
          for (int off = 8; off; off >>= 1) e += __shfl_xor(e, off);
          if ((lane & 15) == 0) {
            size_t o = ((size_t)row * nblkx + blockIdx.x) * 2;
            pms[o] = m; pms[o + 1] = e;
          }
        }
    }
  }
}

// ------------- reduce combine partials (16) + bias + relu -> packed x -------------
__global__ __launch_bounds__(256) void k_reduce_comb(
    const float* __restrict__ parts, const float* __restrict__ bias,
    unsigned short* __restrict__ aX)
{
  int idx = blockIdx.x * 256 + threadIdx.x;  // B_*H_
  int b = idx >> 10, j = idx & (H_ - 1);
  float s = bias[j];
  #pragma unroll
  for (int p = 0; p < 16; ++p) s += parts[(size_t)p * B_ * H_ + idx];
  s = fmaxf(s, 0.f);
  aX[packIdx(b, j)] = f2bf(s);
}

// ------------- GRU gates from split partials (4+4) -> h_new (+packed) -------------
__global__ __launch_bounds__(256) void k_gate(
    const float* __restrict__ giP, const float* __restrict__ ghP,
    const float* __restrict__ b_ih, const float* __restrict__ b_hh,
    const float* __restrict__ hidden, float* __restrict__ hnew,
    unsigned short* __restrict__ aHn)
{
  int idx = blockIdx.x * 256 + threadIdx.x;  // B_*H_
  int b = idx >> 10, j = idx & (H_ - 1);
  size_t base = (size_t)b * 3 * H_;
  float ir = b_ih[j], iz = b_ih[H_ + j], in_ = b_ih[2 * H_ + j];
  float hr = b_hh[j], hz = b_hh[H_ + j], hn = b_hh[2 * H_ + j];
  #pragma unroll
  for (int p = 0; p < 4; ++p) {
    const float* gi = giP + (size_t)p * B_ * 3 * H_ + base;
    const float* gh = ghP + (size_t)p * B_ * 3 * H_ + base;
    ir += gi[j]; iz += gi[H_ + j]; in_ += gi[2 * H_ + j];
    hr += gh[j]; hz += gh[H_ + j]; hn += gh[2 * H_ + j];
  }
  float r = 1.f / (1.f + __expf(-(ir + hr)));
  float z = 1.f / (1.f + __expf(-(iz + hz)));
  float n = tanhf(in_ + r * hn);
  float h = hidden[idx];
  float hv = (1.f - z) * n + z * h;
  hnew[idx] = hv;
  aHn[packIdx(b, j)] = f2bf(hv);
}

// ------------- log_softmax: per-block redundant reduce of pms + subtract -------------
#define SL_ 6283
__global__ __launch_bounds__(256) void k_lsub(
    float* __restrict__ logits, const float* __restrict__ pms, int nblk)
{
  __shared__ float sm[4], ss[4], sc;
  int b = blockIdx.x, sl = blockIdx.y, t = threadIdx.x;
  float M = -1e30f, S = 0.f;
  for (int i = t; i < nblk; i += 256) {
    float m = pms[((size_t)b * nblk + i) * 2];
    float s = pms[((size_t)b * nblk + i) * 2 + 1];
    float nm = fmaxf(M, m);
    S = S * __expf(M - nm) + s * __expf(m - nm);
    M = nm;
  }
  #pragma unroll
  for (int off = 32; off; off >>= 1) {
    float m2 = __shfl_xor(M, off), s2 = __shfl_xor(S, off);
    float nm = fmaxf(M, m2);
    S = S * __expf(M - nm) + s2 * __expf(m2 - nm);
    M = nm;
  }
  if ((t & 63) == 0) { sm[t >> 6] = M; ss[t >> 6] = S; }
  __syncthreads();
  if (t == 0) {
    float Mf = sm[0], Sf = ss[0];
    #pragma unroll
    for (int i = 1; i < 4; ++i) {
      float nm = fmaxf(Mf, sm[i]);
      Sf = Sf * __expf(Mf - nm) + ss[i] * __expf(sm[i] - nm);
      Mf = nm;
    }
    sc = Mf + logf(Sf);
  }
  __syncthreads();
  float c = sc;
  int v0 = sl * SL_;
  int v1 = v0 + SL_; if (v1 > V_) v1 = V_;
  float* row = logits + (size_t)b * V_;
  for (int v = v0 + t; v < v1; v += 256) row[v] -= c;
}

extern "C" void kernel_launch(void* const* d_in, const int* in_sizes, int n_in,
                              void* d_out, int out_size, void* d_ws, size_t ws_size,
                              hipStream_t stream)
{
  const int*   input  = (const int*)d_in[0];
  const float* hidden = (const float*)d_in[1];
  const float* enc    = (const float*)d_in[2];
  const float* emb    = (const float*)d_in[3];
  const float* attn_W = (const float*)d_in[4];
  const float* attn_b = (const float*)d_in[5];
  const float* comb_W = (const float*)d_in[6];
  const float* comb_b = (const float*)d_in[7];
  const float* W_ih   = (const float*)d_in[8];
  const float* W_hh   = (const float*)d_in[9];
  const float* b_ih   = (const float*)d_in[10];
  const float* b_hh   = (const float*)d_in[11];
  const float* out_W  = (const float*)d_in[12];
  const float* out_b  = (const float*)d_in[13];

  float* out    = (float*)d_out;
  float* logits = out;                        // [B,V]
  float* hnew   = out + (size_t)B_ * V_;      // [1,B,H]
  float* attnw  = hnew + (size_t)B_ * H_;     // [B,L]

  const int NBLK = (V_ + 63) / 64;            // 786
  char* ws = (char*)d_ws;
  unsigned short* aXa = (unsigned short*)(ws);                 // 512K
  unsigned short* aH  = (unsigned short*)(ws + 524288);        // 256K
  unsigned short* aX  = (unsigned short*)(ws + 786432);        // 256K
  unsigned short* aHn = (unsigned short*)(ws + 1048576);       // 256K
  float* wbuf  = (float*)(ws + 1310720);                       // 32K
  float* lbuf  = (float*)(ws + 1343488);                       // 32K
  float* pms   = (float*)(ws + 1376256);                       // 805K
  // scratch (aliased): combP (16 x 512K) consumed by k_reduce_comb BEFORE
  // giP/ghP are produced by the gi|gh GEMM.
  float* combP = (float*)(ws + 2185216);                       // 8MB
  float* giP   = (float*)(ws + 2185216);                       // 6MB (aliases combP)
  float* ghP   = (float*)(ws + 2185216 + 6291456);             // 6MB

  // 1. pack embedded + hidden
  k_embh<<<512, 256, 0, stream>>>(input, hidden, emb, aXa, aH);
  // 2. attention logits (wave per (b,l))
  k_alog<<<(B_ * L_) / 4, 256, 0, stream>>>(input, hidden, emb, attn_W, attn_b, lbuf);
  // 3. attention softmax
  k_asm<<<B_ / 4, 256, 0, stream>>>(lbuf, attnw, wbuf);
  // 4. attention weighted sum; pack into aXa hi
  k_app<<<dim3(B_, 4), 256, 0, stream>>>(enc, wbuf, aXa);
  // 5. combine GEMM: K=2048 (64 chunks), 16 splits x 4 chunks
  k_gemm<<<dim3(16, 16), 256, 0, stream>>>(aXa, nullptr, comb_W, nullptr, nullptr,
                                           nullptr, combP, nullptr, nullptr,
                                           2 * H_, H_, 4, 0, 0);
  // 6. reduce + bias + relu -> packed x
  k_reduce_comb<<<(B_ * H_) / 256, 256, 0, stream>>>(combP, comb_b, aX);
  // 7. fused gi|gh GEMMs: K=1024 (32 chunks), each 4 splits x 8 chunks
  k_gemm<<<dim3(48, 8), 256, 0, stream>>>(aX, aH, W_ih, W_hh, nullptr,
                                          nullptr, giP, ghP, nullptr,
                                          H_, 3 * H_, 8, 4, 0);
  // 8. gates -> h_new (out) + packed h_new
  k_gate<<<(B_ * H_) / 256, 256, 0, stream>>>(giP, ghP, b_ih, b_hh, hidden, hnew, aHn);
  // 9. projection + bias + softmax partials (K=1024 -> 32 chunks, no split)
  k_gemm<<<dim3(NBLK, 1), 256, 0, stream>>>(aHn, nullptr, out_W, nullptr, out_b,
                                            logits, nullptr, nullptr, pms,
                                            H_, V_, 32, 0, NBLK);
  // 10. fused reduce + subtract
  k_lsub<<<dim3(B_, 8), 256, 0, stream>>>(logits, pms, NBLK);
}

// Round 7
// 130.233 us; speedup vs baseline: 1.1357x; 1.0376x over previous
//
#include <hip/hip_runtime.h>
#include <hip/hip_bf16.h>

#define B_ 128
#define H_ 1024
#define L_ 60
#define V_ 50257

typedef __attribute__((ext_vector_type(8))) short bf16x8;
typedef __attribute__((ext_vector_type(4))) float f32x4;

__device__ __forceinline__ unsigned short f2bf(float f) {
  union { __hip_bfloat16 h; unsigned short u; } v;
  v.h = __float2bfloat16(f);
  return v.u;
}

__device__ __forceinline__ bf16x8 cvt8(float4 a, float4 b) {
  union { bf16x8 v; __hip_bfloat16 h[8]; } u;
  u.h[0] = __float2bfloat16(a.x); u.h[1] = __float2bfloat16(a.y);
  u.h[2] = __float2bfloat16(a.z); u.h[3] = __float2bfloat16(a.w);
  u.h[4] = __float2bfloat16(b.x); u.h[5] = __float2bfloat16(b.y);
  u.h[6] = __float2bfloat16(b.z); u.h[7] = __float2bfloat16(b.w);
  return u.v;
}

__device__ __forceinline__ void gl_lds16(const void* g, void* l) {
  __builtin_amdgcn_global_load_lds(
      (const __attribute__((address_space(1))) unsigned int*)g,
      (__attribute__((address_space(3))) unsigned int*)l, 16, 0, 0);
}

#define SBAR()   __builtin_amdgcn_s_barrier()
#define SCHED0() __builtin_amdgcn_sched_barrier(0)
__device__ __forceinline__ void vwait6() { asm volatile("s_waitcnt vmcnt(6)" ::: "memory"); }
__device__ __forceinline__ void vwait0() { asm volatile("s_waitcnt vmcnt(0)" ::: "memory"); }

// bf16 A-fragment pack position for MFMA 16x16x32 (verified R1-R6):
// fragment ((s*8+bm)*64+lane), elem j ; lane holds A[row=(bm*16)+(l&15)][k=s*32+(l>>4)*8+j]
__device__ __forceinline__ size_t packIdx(int b, int k) {
  int s = k >> 5;
  int bm = b >> 4;
  int lane = (b & 15) | (((k >> 3) & 3) << 4);
  return ((size_t)((s * 8 + bm) * 64 + lane) << 3) | (size_t)(k & 7);
}

// ------------- fused front: pack embedded+hidden (bx<512) | attn logits -------------
__global__ __launch_bounds__(256) void k_front(
    const int* __restrict__ input, const float* __restrict__ hidden,
    const float* __restrict__ emb, const float* __restrict__ attn_W,
    const float* __restrict__ attn_b, unsigned short* __restrict__ aXa,
    unsigned short* __restrict__ aH, float* __restrict__ lbuf)
{
  int bx = blockIdx.x;
  if (bx < 512) {
    int idx = bx * 256 + threadIdx.x;          // B_*H_
    int b = idx >> 10, j = idx & (H_ - 1);
    float e = emb[(size_t)input[b] * H_ + j];
    float h = hidden[idx];
    size_t p = packIdx(b, j);
    aXa[p] = f2bf(e);
    aH[p]  = f2bf(h);
  } else {
    int t = threadIdx.x, wv = t >> 6, lane = t & 63;
    int task = (bx - 512) * 4 + wv;            // 0 .. B_*L_-1
    int b = task / L_, l = task - b * L_;
    const float* erow = emb + (size_t)input[b] * H_;
    const float* hrow = hidden + (size_t)b * H_;
    const float* wr = attn_W + (size_t)l * (2 * H_);
    float acc = 0.f;
    #pragma unroll 4
    for (int i = 0; i < 16; ++i) {
      int m = lane + i * 64;
      acc += erow[m] * wr[m] + hrow[m] * wr[H_ + m];
    }
    #pragma unroll
    for (int off = 32; off; off >>= 1) acc += __shfl_xor(acc, off);
    if (lane == 0) lbuf[b * 64 + l] = acc + attn_b[l];
  }
}

// ------------- attn softmax (redundant per block) + weighted sum + pack -------------
__global__ __launch_bounds__(256) void k_appsm(
    const float* __restrict__ enc, const float* __restrict__ lbuf,
    float* __restrict__ attnw, unsigned short* __restrict__ aXa)
{
  __shared__ float sWt[64];
  int b = blockIdx.x, q = blockIdx.y, t = threadIdx.x;
  if (t < 64) {
    float v = (t < L_) ? lbuf[b * 64 + t] : -1e30f;
    float m = v;
    #pragma unroll
    for (int off = 32; off; off >>= 1) m = fmaxf(m, __shfl_xor(m, off));
    float e = (t < L_) ? __expf(v - m) : 0.f;
    float s = e;
    #pragma unroll
    for (int off = 32; off; off >>= 1) s += __shfl_xor(s, off);
    float w = e / s;
    sWt[t] = w;
    if (q == 0 && t < L_) attnw[b * L_ + t] = w;
  }
  __syncthreads();
  int col = q * 256 + t;
  const float* eb = enc + (size_t)b * L_ * H_ + col;
  float acc = 0.f;
  #pragma unroll 4
  for (int l = 0; l < L_; ++l) acc += sWt[l] * eb[(size_t)l * H_];
  aXa[packIdx(b, H_ + col)] = f2bf(acc);
}

// ------------- LDS-staged MFMA GEMM, counted-vmcnt, wave = 64 rows x 32 cols -------------
// C[b,n] = sum_k A[b,k]*W[n,k]. Tile 128(B) x 64(N), chunk = 32 k.
// W: 8KB f32/chunk staged via global_load_lds (XOR-swizzled both sides), 2-buffered.
// A: per-wave 4 bm fragments global->VGPR, reg-double-buffered (static roles).
// Wave wv: rows [64*(wv>>1), +64) x cols [32*(wv&1), +32)  ->  B-side work 2x
// (vs 4x in the rows-only split): per chunk/wave 4 ds_read_b128 + 2 cvt8 + 8 MFMA.
// VMEM/chunk = 2 gl_lds + 4 A = 6 -> vwait6 == "previous chunk landed".
// Proven R3/R6 2-barrier fence skeleton; vmcnt never drained mid-loop.
__global__ __launch_bounds__(256, 5) void k_gemm(
    const unsigned short* __restrict__ Apk, const unsigned short* __restrict__ Apk2,
    const float* __restrict__ Wt, const float* __restrict__ Wt2,
    const float* __restrict__ bias, float* __restrict__ Cdir,
    float* __restrict__ Cpart, float* __restrict__ Cpart2,
    float* __restrict__ pms, int K, int N, int nchunks, int halfY, int nblkx)
{
  __shared__ __align__(16) float bufW0[64 * 32];   // 8KB
  __shared__ __align__(16) float bufW1[64 * 32];   // 8KB
  int t = threadIdx.x, wv = t >> 6, lane = t & 63;
  int y = blockIdx.y;
  const unsigned short* A = Apk;
  const float* W = Wt;
  float* CP = Cpart;
  int sidx = y;
  if (halfY && y >= halfY) { A = Apk2; W = Wt2; CP = Cpart2; sidx = y - halfY; }
  int chunk0 = sidx * nchunks;
  int n0 = blockIdx.x * 64;
  int ch = wv & 1;            // col half: nc in {2ch, 2ch+1}
  int bm0 = (wv >> 1) * 4;    // row quarter-base: 4 bms
  int srow8 = lane >> 3;
  int sch = lane & 7;
  int g = lane >> 4;

  f32x4 acc[4][2];
  #pragma unroll
  for (int i = 0; i < 4; ++i)
    #pragma unroll
    for (int j = 0; j < 2; ++j) acc[i][j] = (f32x4){0.f, 0.f, 0.f, 0.f};

  auto SW = [&](int kc, float* buf) {
    #pragma unroll
    for (int i = 0; i < 2; ++i) {
      int r = wv * 16 + i * 8 + srow8;
      int gcol = n0 + r; gcol = (gcol < N) ? gcol : (N - 1);
      int c = sch ^ (r & 7);
      const float* src = W + (size_t)gcol * K + (size_t)kc * 32 + c * 4;
      gl_lds16(src, buf + (wv * 16 + i * 8) * 32);
    }
  };
  const bf16x8* apg = (const bf16x8*)A;
  auto LA = [&](int kc, bf16x8* x) {
    #pragma unroll
    for (int j = 0; j < 4; ++j)
      x[j] = apg[((size_t)kc * 8 + bm0 + j) * 64 + lane];
  };
  auto COMP = [&](const float* bw, const bf16x8* a) {
    #pragma unroll
    for (int nci = 0; nci < 2; ++nci) {
      int rr = (ch * 2 + nci) * 16 + (lane & 15);
      int c0 = (g * 2) ^ (rr & 7);
      int c1 = (g * 2 + 1) ^ (rr & 7);
      float4 w0 = *(const float4*)&bw[rr * 32 + c0 * 4];
      float4 w1 = *(const float4*)&bw[rr * 32 + c1 * 4];
      bf16x8 bfr = cvt8(w0, w1);
      #pragma unroll
      for (int j = 0; j < 4; ++j)
        acc[j][nci] = __builtin_amdgcn_mfma_f32_16x16x32_bf16(a[j], bfr, acc[j][nci], 0, 0, 0);
    }
  };

  bf16x8 aA[4], aB[4];
  SW(chunk0, bufW0);     LA(chunk0, aA);
  SW(chunk0 + 1, bufW1); LA(chunk0 + 1, aB);
  vwait6(); SCHED0(); SBAR();

  for (int kk = 0; kk < nchunks; kk += 2) {
    COMP(bufW0, aA);                            // chunk kk
    SCHED0(); SBAR();                           // all waves done with bufW0
    if (kk + 2 < nchunks) { SW(chunk0 + kk + 2, bufW0); LA(chunk0 + kk + 2, aA); vwait6(); }
    else vwait0();
    SCHED0(); SBAR();                           // bufW1 / aB landed everywhere
    COMP(bufW1, aB);                            // chunk kk+1
    if (kk + 2 < nchunks) {
      SCHED0(); SBAR();                         // all waves done with bufW1
      if (kk + 3 < nchunks) { SW(chunk0 + kk + 3, bufW1); LA(chunk0 + kk + 3, aB); vwait6(); }
      else vwait0();
      SCHED0(); SBAR();                         // bufW0 / aA landed everywhere
    }
  }

  int cols[2]; float bv[2];
  #pragma unroll
  for (int nci = 0; nci < 2; ++nci) {
    int c = n0 + (ch * 2 + nci) * 16 + (lane & 15);
    cols[nci] = c;
    bv[nci] = (bias && c < N) ? bias[c] : 0.f;
  }
  int rb = (lane >> 4) * 4;
  if (CP) {
    float* dst = CP + (size_t)sidx * B_ * N;
    #pragma unroll
    for (int bm = 0; bm < 4; ++bm)
      #pragma unroll
      for (int r = 0; r < 4; ++r) {
        int row = (bm0 + bm) * 16 + rb + r;
        #pragma unroll
        for (int nci = 0; nci < 2; ++nci)
          if (cols[nci] < N) dst[(size_t)row * N + cols[nci]] = acc[bm][nci][r];
      }
  } else {
    #pragma unroll
    for (int bm = 0; bm < 4; ++bm)
      #pragma unroll
      for (int r = 0; r < 4; ++r) {
        int row = (bm0 + bm) * 16 + rb + r;
        #pragma unroll
        for (int nci = 0; nci < 2; ++nci)
          if (cols[nci] < N) Cdir[(size_t)row * N + cols[nci]] = acc[bm][nci][r] + bv[nci];
      }
    if (pms) {
      // per-(row, 32-col-half) partials: index 2*blockIdx.x + ch within 2*nblkx
      #pragma unroll
      for (int bm = 0; bm < 4; ++bm)
        #pragma unroll
        for (int r = 0; r < 4; ++r) {
          int row = (bm0 + bm) * 16 + rb + r;
          float m = -1e30f;
          #pragma unroll
          for (int nci = 0; nci < 2; ++nci)
            if (cols[nci] < N) m = fmaxf(m, acc[bm][nci][r] + bv[nci]);
          #pragma unroll
          for (int off = 8; off; off >>= 1) m = fmaxf(m, __shfl_xor(m, off));
          float e = 0.f;
          #pragma unroll
          for (int nci = 0; nci < 2; ++nci)
            if (cols[nci] < N) e += __expf(acc[bm][nci][r] + bv[nci] - m);
          #pragma unroll
          for (int off = 8; off; off >>= 1) e += __shfl_xor(e, off);
          if ((lane & 15) == 0) {
            size_t o = ((size_t)row * (2 * nblkx) + blockIdx.x * 2 + ch) * 2;
            pms[o] = m; pms[o + 1] = e;
          }
        }
    }
  }
}

// ------------- reduce combine partials (16) + bias + relu -> packed x -------------
__global__ __launch_bounds__(256) void k_reduce_comb(
    const float* __restrict__ parts, const float* __restrict__ bias,
    unsigned short* __restrict__ aX)
{
  int idx = blockIdx.x * 256 + threadIdx.x;  // B_*H_
  int b = idx >> 10, j = idx & (H_ - 1);
  float s = bias[j];
  #pragma unroll
  for (int p = 0; p < 16; ++p) s += parts[(size_t)p * B_ * H_ + idx];
  s = fmaxf(s, 0.f);
  aX[packIdx(b, j)] = f2bf(s);
}

// ------------- GRU gates from split partials (4+4) -> h_new (+packed) -------------
__global__ __launch_bounds__(256) void k_gate(
    const float* __restrict__ giP, const float* __restrict__ ghP,
    const float* __restrict__ b_ih, const float* __restrict__ b_hh,
    const float* __restrict__ hidden, float* __restrict__ hnew,
    unsigned short* __restrict__ aHn)
{
  int idx = blockIdx.x * 256 + threadIdx.x;  // B_*H_
  int b = idx >> 10, j = idx & (H_ - 1);
  size_t base = (size_t)b * 3 * H_;
  float ir = b_ih[j], iz = b_ih[H_ + j], in_ = b_ih[2 * H_ + j];
  float hr = b_hh[j], hz = b_hh[H_ + j], hn = b_hh[2 * H_ + j];
  #pragma unroll
  for (int p = 0; p < 4; ++p) {
    const float* gi = giP + (size_t)p * B_ * 3 * H_ + base;
    const float* gh = ghP + (size_t)p * B_ * 3 * H_ + base;
    ir += gi[j]; iz += gi[H_ + j]; in_ += gi[2 * H_ + j];
    hr += gh[j]; hz += gh[H_ + j]; hn += gh[2 * H_ + j];
  }
  float r = 1.f / (1.f + __expf(-(ir + hr)));
  float z = 1.f / (1.f + __expf(-(iz + hz)));
  float n = tanhf(in_ + r * hn);
  float h = hidden[idx];
  float hv = (1.f - z) * n + z * h;
  hnew[idx] = hv;
  aHn[packIdx(b, j)] = f2bf(hv);
}

// ------------- log_softmax: per-block redundant reduce of pms + subtract -------------
#define SL_ 6283
__global__ __launch_bounds__(256) void k_lsub(
    float* __restrict__ logits, const float* __restrict__ pms, int nblk2)
{
  __shared__ float sm[4], ss[4], sc;
  int b = blockIdx.x, sl = blockIdx.y, t = threadIdx.x;
  float M = -1e30f, S = 0.f;
  for (int i = t; i < nblk2; i += 256) {
    float m = pms[((size_t)b * nblk2 + i) * 2];
    float s = pms[((size_t)b * nblk2 + i) * 2 + 1];
    float nm = fmaxf(M, m);
    S = S * __expf(M - nm) + s * __expf(m - nm);
    M = nm;
  }
  #pragma unroll
  for (int off = 32; off; off >>= 1) {
    float m2 = __shfl_xor(M, off), s2 = __shfl_xor(S, off);
    float nm = fmaxf(M, m2);
    S = S * __expf(M - nm) + s2 * __expf(m2 - nm);
    M = nm;
  }
  if ((t & 63) == 0) { sm[t >> 6] = M; ss[t >> 6] = S; }
  __syncthreads();
  if (t == 0) {
    float Mf = sm[0], Sf = ss[0];
    #pragma unroll
    for (int i = 1; i < 4; ++i) {
      float nm = fmaxf(Mf, sm[i]);
      Sf = Sf * __expf(Mf - nm) + ss[i] * __expf(sm[i] - nm);
      Mf = nm;
    }
    sc = Mf + logf(Sf);
  }
  __syncthreads();
  float c = sc;
  int v0 = sl * SL_;
  int v1 = v0 + SL_; if (v1 > V_) v1 = V_;
  float* row = logits + (size_t)b * V_;
  for (int v = v0 + t; v < v1; v += 256) row[v] -= c;
}

extern "C" void kernel_launch(void* const* d_in, const int* in_sizes, int n_in,
                              void* d_out, int out_size, void* d_ws, size_t ws_size,
                              hipStream_t stream)
{
  const int*   input  = (const int*)d_in[0];
  const float* hidden = (const float*)d_in[1];
  const float* enc    = (const float*)d_in[2];
  const float* emb    = (const float*)d_in[3];
  const float* attn_W = (const float*)d_in[4];
  const float* attn_b = (const float*)d_in[5];
  const float* comb_W = (const float*)d_in[6];
  const float* comb_b = (const float*)d_in[7];
  const float* W_ih   = (const float*)d_in[8];
  const float* W_hh   = (const float*)d_in[9];
  const float* b_ih   = (const float*)d_in[10];
  const float* b_hh   = (const float*)d_in[11];
  const float* out_W  = (const float*)d_in[12];
  const float* out_b  = (const float*)d_in[13];

  float* out    = (float*)d_out;
  float* logits = out;                        // [B,V]
  float* hnew   = out + (size_t)B_ * V_;      // [1,B,H]
  float* attnw  = hnew + (size_t)B_ * H_;     // [B,L]

  const int NBLK = (V_ + 63) / 64;            // 786
  char* ws = (char*)d_ws;
  unsigned short* aXa = (unsigned short*)(ws);                 // 512K
  unsigned short* aH  = (unsigned short*)(ws + 524288);        // 256K
  unsigned short* aX  = (unsigned short*)(ws + 786432);        // 256K
  unsigned short* aHn = (unsigned short*)(ws + 1048576);       // 256K
  float* lbuf  = (float*)(ws + 1310720);                       // 32K
  float* pms   = (float*)(ws + 1343488);                       // 1.61M (128*1572*8B)
  // scratch (aliased): combP (16 x 512K) consumed by k_reduce_comb BEFORE
  // giP/ghP are produced by the gi|gh GEMM.
  float* combP = (float*)(ws + 4194304);                       // 8MB
  float* giP   = (float*)(ws + 4194304);                       // 6MB (aliases combP)
  float* ghP   = (float*)(ws + 4194304 + 6291456);             // 6MB

  // 1. fused: pack embedded+hidden | attention logits
  k_front<<<512 + (B_ * L_) / 4, 256, 0, stream>>>(input, hidden, emb, attn_W, attn_b,
                                                   aXa, aH, lbuf);
  // 2. softmax (redundant per block) + weighted sum; pack into aXa hi
  k_appsm<<<dim3(B_, 4), 256, 0, stream>>>(enc, lbuf, attnw, aXa);
  // 3. combine GEMM: K=2048 (64 chunks), 16 splits x 4 chunks
  k_gemm<<<dim3(16, 16), 256, 0, stream>>>(aXa, nullptr, comb_W, nullptr, nullptr,
                                           nullptr, combP, nullptr, nullptr,
                                           2 * H_, H_, 4, 0, 0);
  // 4. reduce + bias + relu -> packed x
  k_reduce_comb<<<(B_ * H_) / 256, 256, 0, stream>>>(combP, comb_b, aX);
  // 5. fused gi|gh GEMMs: K=1024 (32 chunks), each 4 splits x 8 chunks
  k_gemm<<<dim3(48, 8), 256, 0, stream>>>(aX, aH, W_ih, W_hh, nullptr,
                                          nullptr, giP, ghP, nullptr,
                                          H_, 3 * H_, 8, 4, 0);
  // 6. gates -> h_new (out) + packed h_new
  k_gate<<<(B_ * H_) / 256, 256, 0, stream>>>(giP, ghP, b_ih, b_hh, hidden, hnew, aHn);
  // 7. projection + bias + softmax partials (K=1024 -> 32 chunks, no split)
  k_gemm<<<dim3(NBLK, 1), 256, 0, stream>>>(aHn, nullptr, out_W, nullptr, out_b,
                                            logits, nullptr, nullptr, pms,
                                            H_, V_, 32, 0, NBLK);
  // 8. fused reduce + subtract (2*NBLK partials per row)
  k_lsub<<<dim3(B_, 8), 256, 0, stream>>>(logits, pms, 2 * NBLK);
}